// Round 9
// baseline (2272.475 us; speedup 1.0000x reference)
//
#include <hip/hip_runtime.h>
#include <math.h>

#define K_NN 11
#define B_   1024
#define D_   64
#define A_   4
#define C_   50000
#define NCH  4
#define CPC  12500               // candidates per chunk
#define NTPC 196                 // ceil(12500/64) tiles per chunk
#define RW   68                  // padded LDS row stride (floats): bank-uniform
#define TSZ  (64 * RW)           // 4352 floats = 17,408 B per buffer

// ---------------- K0: s2[a,c] = sum(ts[a,c,:]^2) ----------------
__global__ __launch_bounds__(256) void s2_kernel(const float* __restrict__ ts,
                                                 float* __restrict__ s2g) {
  const int gwid = (blockIdx.x * 256 + threadIdx.x) >> 6;
  const int lane = threadIdx.x & 63;
  const int r0 = gwid * 16;
  if (r0 >= A_ * C_) return;
  const float4* t4 = (const float4*)ts;
  #pragma unroll
  for (int i = 0; i < 4; ++i) {
    const int fi = i * 64 + lane;
    const int r  = r0 + (fi >> 4);
    const int k  = fi & 15;
    float4 v = t4[(size_t)r * 16 + k];
    float acc = v.x*v.x + v.y*v.y + v.z*v.z + v.w*v.w;
    #pragma unroll
    for (int off = 1; off < 16; off <<= 1) acc += __shfl_xor(acc, off, 64);
    if ((lane & 15) == 0) s2g[r] = acc;
  }
}

// ---------------- K1: r8 skeleton, batched combine, 1 ballot/row ----------
// grid 512 = 32 rowgroups x 4 a x 4 ch; block 512 thr = 8 waves, 4 rows/wave.
// Lane half h covers dims 32h..32h+31 of cands u and u+32; after the batched
// xor-32 swap each lane owns cand c0+lane's full score -> one ballot per row.

#define SELROW(R)                                                            \
  {                                                                          \
    const int cid = c0 + lane;                                               \
    const float scv = sc[R];                                                 \
    const bool pass = (cid < cend) &&                                        \
        ((scv < tau[R]) || (scv == tau[R] && cid < tix[R]));                 \
    unsigned long long m_ = __ballot(pass);                                  \
    while (m_) {                                                             \
      const int l_ = __ffsll(m_) - 1;                                        \
      m_ &= m_ - 1;                                                          \
      const float ssc = __uint_as_float(                                     \
          __builtin_amdgcn_readlane(__float_as_uint(scv), l_));              \
      const int sid = c0 + l_;                                               \
      if ((ssc < tau[R]) || (ssc == tau[R] && sid < tix[R])) {               \
        const bool own = (lane == (R));                                      \
        _Pragma("unroll")                                                    \
        for (int j = K_NN - 1; j >= 1; --j) {                                \
          const bool  s1 = (best[j-1] > ssc) ||                              \
                           (best[j-1] == ssc && bix[j-1] > sid);             \
          const float nb = s1 ? best[j-1] : ssc;                             \
          const int   ni = s1 ? bix[j-1]  : sid;                             \
          const bool  wr = own && ((best[j] > ssc) ||                        \
                                   (best[j] == ssc && bix[j] > sid));        \
          best[j] = wr ? nb : best[j];                                       \
          bix[j]  = wr ? ni : bix[j];                                        \
        }                                                                    \
        const bool w0 = own && ((best[0] > ssc) ||                           \
                                (best[0] == ssc && bix[0] > sid));           \
        bix[0]  = w0 ? sid : bix[0];                                         \
        best[0] = w0 ? ssc : best[0];                                        \
        tau[R] = __uint_as_float(                                            \
            __builtin_amdgcn_readlane(__float_as_uint(best[K_NN-1]), (R)));  \
        tix[R] = __builtin_amdgcn_readlane(bix[K_NN-1], (R));                \
      }                                                                      \
    }                                                                        \
  }

// coalesced global loads: f = tid + 512j -> cand cb+(f>>4), float4 (f&15)
#define LOADS(T)                                                             \
  {                                                                          \
    const int cb = cbase + (T) * 64;                                         \
    _Pragma("unroll")                                                        \
    for (int j = 0; j < 2; ++j) {                                            \
      const int f = tid + 512 * j;                                           \
      const int c = min(cb + (f >> 4), C_ - 1);                              \
      stg[j] = *(const float4*)(tsa + (size_t)c * 64 + 4 * (f & 15));        \
    }                                                                        \
  }
// pad-68 writes: measured conflict-free (r8)
#define WRITES(BUF)                                                          \
  {                                                                          \
    float* dst = &sb[BUF][0];                                                \
    _Pragma("unroll")                                                        \
    for (int j = 0; j < 2; ++j) {                                            \
      const int f = tid + 512 * j;                                           \
      *(float4*)&dst[(f >> 4) * RW + 4 * (f & 15)] = stg[j];                 \
    }                                                                        \
  }

__global__ __launch_bounds__(512) void qec_kernel(
    const float* __restrict__ obs, const float* __restrict__ ts,
    const float* __restrict__ s2g, float* __restrict__ pscore,
    int* __restrict__ pidx)
{
  __shared__ float sb[2][TSZ];              // 34,816 B

  const int tid  = threadIdx.x;
  const int lane = tid & 63;
  const int w    = tid >> 6;
  const int x    = blockIdx.x & 15;         // (a,ch) -> stable XCD slices
  const int a    = x >> 2;
  const int ch   = x & 3;
  const int rg   = blockIdx.x >> 4;         // 0..31
  const int b0w  = rg * 32 + w * 4;         // this wave's 4 rows

  const int h = lane >> 5;                  // dim half
  const int u = lane & 31;                  // cand sub-index

  const float* tsa = ts  + (size_t)a * C_ * 64;
  const float* s2a = s2g + (size_t)a * C_;
  const int cbase = ch * CPC;
  const int cend  = cbase + CPC;

  // obs half-rows: o[r][q] = obs[b0w+r][32h+4q .. +3]
  float4 o[4][8];
  #pragma unroll
  for (int r = 0; r < 4; ++r)
    #pragma unroll
    for (int q = 0; q < 8; ++q)
      o[r][q] = *(const float4*)(obs + (size_t)(b0w + r) * 64 + 32 * h + 4 * q);

  float best[K_NN]; int bix[K_NN];
  float tau[4]; int tix[4];
  #pragma unroll
  for (int j = 0; j < K_NN; ++j) { best[j] = INFINITY; bix[j] = 0x7fffffff; }
  #pragma unroll
  for (int r = 0; r < 4; ++r) { tau[r] = INFINITY; tix[r] = 0x7fffffff; }

  float4 stg[2];

  LOADS(0);

  for (int T = 0; T < NTPC; ++T) {
    const int c0 = cbase + T * 64;

    WRITES(T & 1);
    if (T + 1 < NTPC) LOADS(T + 1);
    const float sA = s2a[min(c0 + u, C_ - 1)];
    const float sB = s2a[min(c0 + 32 + u, C_ - 1)];

    __syncthreads();

    // compute: lane's cands u and u+32 on its 32 dims (pad-68, conflict-free)
    float accA[4] = {0.f, 0.f, 0.f, 0.f};
    float accB[4] = {0.f, 0.f, 0.f, 0.f};
    {
      const float* bp = &sb[T & 1][0];
      const int baseA = u * RW + 32 * h;
      const int baseB = (u + 32) * RW + 32 * h;
      #pragma unroll
      for (int q = 0; q < 8; ++q) {
        const float4 cA = *(const float4*)&bp[baseA + 4 * q];
        const float4 cB = *(const float4*)&bp[baseB + 4 * q];
        #pragma unroll
        for (int r = 0; r < 4; ++r) {
          accA[r] = fmaf(cA.x, o[r][q].x, accA[r]);
          accA[r] = fmaf(cA.y, o[r][q].y, accA[r]);
          accA[r] = fmaf(cA.z, o[r][q].z, accA[r]);
          accA[r] = fmaf(cA.w, o[r][q].w, accA[r]);
          accB[r] = fmaf(cB.x, o[r][q].x, accB[r]);
          accB[r] = fmaf(cB.y, o[r][q].y, accB[r]);
          accB[r] = fmaf(cB.z, o[r][q].z, accB[r]);
          accB[r] = fmaf(cB.w, o[r][q].w, accB[r]);
        }
      }
    }

    // batched combine: issue ALL 8 xor-32 swaps before any ballot
    float sc[4];
    {
      float pA[4], pB[4];
      #pragma unroll
      for (int r = 0; r < 4; ++r) { pA[r] = __shfl_xor(accA[r], 32, 64);
                                    pB[r] = __shfl_xor(accB[r], 32, 64); }
      #pragma unroll
      for (int r = 0; r < 4; ++r) {
        const float scA = fmaf(-2.f, accA[r] + pA[r], sA);
        const float scB = fmaf(-2.f, accB[r] + pB[r], sB);
        sc[r] = (lane < 32) ? scA : scB;    // lane owns cand c0+lane
      }
    }

    SELROW(0) SELROW(1) SELROW(2) SELROW(3)

    __syncthreads();
  }

  // epilogue: lane r (0..3) owns row b0w+r
  if (lane < 4) {
    const int b = b0w + lane;
    const size_t base = (((size_t)b * A_ + a) * NCH + ch) * K_NN;
    #pragma unroll
    for (int j = 0; j < K_NN; ++j) {
      pscore[base + j] = best[j];
      pidx[base + j]   = bix[j];
    }
  }
}

// ---------------- K2: merge partial top-k, gather qvals, mean ----------------
__global__ __launch_bounds__(256) void merge_kernel(
    const float* __restrict__ pscore, const int* __restrict__ pidx,
    const float* __restrict__ qvals, float* __restrict__ qec)
{
  const int tt = blockIdx.x * 256 + threadIdx.x;  // tt = b*A + a
  if (tt >= B_ * A_) return;
  const int a = tt % A_;

  float best[K_NN]; int bix[K_NN];
  #pragma unroll
  for (int j = 0; j < K_NN; ++j) { best[j] = INFINITY; bix[j] = 0x7fffffff; }

  const float* ps = pscore + (size_t)tt * NCH * K_NN;
  const int*   pi = pidx   + (size_t)tt * NCH * K_NN;

  #pragma unroll
  for (int e = 0; e < NCH * K_NN; ++e) {
    float sc = ps[e]; int ci = pi[e];
    bool lt_last = (sc < best[K_NN-1]) || (sc == best[K_NN-1] && ci < bix[K_NN-1]);
    if (lt_last) {
      #pragma unroll
      for (int j = K_NN-1; j >= 1; --j) {
        bool  s1 = (best[j-1] > sc) || (best[j-1] == sc && bix[j-1] > ci);
        float nb = s1 ? best[j-1] : sc;
        int   ni = s1 ? bix[j-1]  : ci;
        bool  wr = (best[j] > sc) || (best[j] == sc && bix[j] > ci);
        if (wr) { best[j] = nb; bix[j] = ni; }
      }
      bool w0 = (best[0] > sc) || (best[0] == sc && bix[0] > ci);
      if (w0) { best[0] = sc; bix[0] = ci; }
    }
  }

  const float* qa = qvals + (size_t)a * C_;
  float s = 0.f;
  #pragma unroll
  for (int j = 0; j < K_NN; ++j) s += qa[bix[j]];
  qec[tt] = s / (float)K_NN;
}

// ---------------- K3: MLP + combine + argmax ----------------
__global__ __launch_bounds__(256) void mlp_kernel(
    const float* __restrict__ obs, const float* __restrict__ qec,
    const float* __restrict__ W1, const float* __restrict__ b1,
    const float* __restrict__ W2, const float* __restrict__ b2,
    const float* __restrict__ W3, const float* __restrict__ b3,
    float* __restrict__ out)
{
  const int wave = threadIdx.x >> 6;
  const int lane = threadIdx.x & 63;
  const int b = blockIdx.x * 4 + wave;

  float xv = obs[(size_t)b * 64 + lane];

  float acc = b1[lane];
  #pragma unroll 8
  for (int d = 0; d < 64; ++d)
    acc = fmaf(__shfl(xv, d, 64), W1[d * 64 + lane], acc);
  float h1 = fmaxf(acc, 0.f);

  float acc2 = b2[lane];
  #pragma unroll 8
  for (int d = 0; d < 64; ++d)
    acc2 = fmaf(__shfl(h1, d, 64), W2[d * 64 + lane], acc2);
  float h2 = fmaxf(acc2, 0.f);

  float p0 = h2 * W3[lane * 4 + 0];
  float p1 = h2 * W3[lane * 4 + 1];
  float p2 = h2 * W3[lane * 4 + 2];
  float p3 = h2 * W3[lane * 4 + 3];
  #pragma unroll
  for (int off = 32; off > 0; off >>= 1) {
    p0 += __shfl_xor(p0, off, 64);
    p1 += __shfl_xor(p1, off, 64);
    p2 += __shfl_xor(p2, off, 64);
    p3 += __shfl_xor(p3, off, 64);
  }

  if (lane == 0) {
    float q0 = 0.5f * (qec[b * 4 + 0] + (p0 + b3[0]));
    float q1 = 0.5f * (qec[b * 4 + 1] + (p1 + b3[1]));
    float q2 = 0.5f * (qec[b * 4 + 2] + (p2 + b3[2]));
    float q3 = 0.5f * (qec[b * 4 + 3] + (p3 + b3[3]));
    int am = 0; float m = q0;
    if (q1 > m) { m = q1; am = 1; }
    if (q2 > m) { m = q2; am = 2; }
    if (q3 > m) { m = q3; am = 3; }
    out[b] = (float)am;
    float* qrow = out + B_ + (size_t)b * 4;
    qrow[0] = q0; qrow[1] = q1; qrow[2] = q2; qrow[3] = q3;
  }
}

extern "C" void kernel_launch(void* const* d_in, const int* in_sizes, int n_in,
                              void* d_out, int out_size, void* d_ws, size_t ws_size,
                              hipStream_t stream) {
  const float* obs = (const float*)d_in[0];
  const float* ts  = (const float*)d_in[1];
  const float* qv  = (const float*)d_in[2];
  const float* W1  = (const float*)d_in[3];
  const float* b1  = (const float*)d_in[4];
  const float* W2  = (const float*)d_in[5];
  const float* b2  = (const float*)d_in[6];
  const float* W3  = (const float*)d_in[7];
  const float* b3  = (const float*)d_in[8];
  float* out = (float*)d_out;

  float* s2g    = (float*)d_ws;                                   // A*C
  float* qec    = s2g + (size_t)A_ * C_;                          // B*A
  float* pscore = qec + (size_t)B_ * A_;                          // B*A*NCH*K
  int*   pidx   = (int*)(pscore + (size_t)B_ * A_ * NCH * K_NN);  // same

  s2_kernel<<<dim3((A_ * C_ / 16 + 3) / 4), dim3(256), 0, stream>>>(ts, s2g);
  qec_kernel<<<dim3(512), dim3(512), 0, stream>>>(obs, ts, s2g, pscore, pidx);
  merge_kernel<<<dim3((B_ * A_ + 255) / 256), dim3(256), 0, stream>>>(pscore, pidx, qv, qec);
  mlp_kernel<<<dim3(B_ / 4), dim3(256), 0, stream>>>(obs, qec, W1, b1, W2, b2, W3, b3, out);
}

// Round 10
// 1005.297 us; speedup vs baseline: 2.2605x; 2.2605x over previous
//
#include <hip/hip_runtime.h>
#include <math.h>

#define K_NN 11
#define B_   1024
#define D_   64
#define A_   4
#define C_   50000
#define NCH  16
#define CCH  3125                // C_/NCH exactly
#define NTF  196                 // ceil(3125/16) 16-cand tiles per chunk
#define CAP  768                 // emit buffer entries per stream
#define QCAP 64                  // LDS queue per (row, wave)
#define EMARG 0.6f               // >> bf16 dot error bound
#define NSTREAM (B_ * A_)
#define NSAMP 782                // samples c = 64j, j < 782 (<= 49984)

typedef __attribute__((ext_vector_type(8))) short short8v;   // 8 bf16
typedef __attribute__((ext_vector_type(4))) float f32x4;

__device__ __forceinline__ unsigned short f2bf(float x) {    // RNE f32->bf16
  unsigned u = __float_as_uint(x);
  u += 0x7fffu + ((u >> 16) & 1u);
  return (unsigned short)(u >> 16);
}

#define LEXLT(SA, IA, SB, IB) (((SA) < (SB)) || ((SA) == (SB) && (IA) < (IB)))

// lex (score,idx) insert into sorted-11 registers (proven pattern, absmax=0)
#define INS11(BS, BI, S, I)                                                  \
  if (LEXLT((S), (I), BS[K_NN-1], BI[K_NN-1])) {                             \
    _Pragma("unroll")                                                        \
    for (int j_ = K_NN - 1; j_ >= 1; --j_) {                                 \
      const bool  s1_ = LEXLT((S), (I), BS[j_-1], BI[j_-1]);                 \
      const float nb_ = s1_ ? BS[j_-1] : (S);                                \
      const int   ni_ = s1_ ? BI[j_-1] : (I);                                \
      if (LEXLT((S), (I), BS[j_], BI[j_])) { BS[j_] = nb_; BI[j_] = ni_; }   \
    }                                                                        \
    if (LEXLT((S), (I), BS[0], BI[0])) { BS[0] = (S); BI[0] = (I); }         \
  }

// ---------------- K0: s2[a,c] = sum(ts[a,c,:]^2)  (exact f32) --------------
__global__ __launch_bounds__(256) void s2_kernel(const float* __restrict__ ts,
                                                 float* __restrict__ s2g) {
  const int gwid = (blockIdx.x * 256 + threadIdx.x) >> 6;
  const int lane = threadIdx.x & 63;
  const int r0 = gwid * 16;
  if (r0 >= A_ * C_) return;
  const float4* t4 = (const float4*)ts;
  #pragma unroll
  for (int i = 0; i < 4; ++i) {
    const int fi = i * 64 + lane;
    const int r  = r0 + (fi >> 4);
    const int k  = fi & 15;
    float4 v = t4[(size_t)r * 16 + k];
    float acc = v.x*v.x + v.y*v.y + v.z*v.z + v.w*v.w;
    #pragma unroll
    for (int off = 1; off < 16; off <<= 1) acc += __shfl_xor(acc, off, 64);
    if ((lane & 15) == 0) s2g[r] = acc;
  }
}

// ---------------- K_prep: cast ts and obs to bf16 --------------------------
__global__ __launch_bounds__(256) void prep_kernel(
    const float* __restrict__ ts, const float* __restrict__ obs,
    unsigned short* __restrict__ tsb, unsigned short* __restrict__ obsb) {
  const long long NT4 = (long long)A_ * C_ * 16;   // float4 groups in ts
  const long long NO4 = (long long)B_ * 16;        // float4 groups in obs
  for (long long i = (long long)blockIdx.x * 256 + threadIdx.x;
       i < NT4 + NO4; i += (long long)gridDim.x * 256) {
    const float4 v = (i < NT4) ? ((const float4*)ts)[i]
                               : ((const float4*)obs)[i - NT4];
    ushort4 o;
    o.x = f2bf(v.x); o.y = f2bf(v.y); o.z = f2bf(v.z); o.w = f2bf(v.w);
    if (i < NT4) ((ushort4*)tsb)[i] = o;
    else         ((ushort4*)obsb)[i - NT4] = o;
  }
}

// ---------------- K_sample: tau = 3rd-smallest exact score of 782 samples --
__global__ __launch_bounds__(256) void sample_kernel(
    const float* __restrict__ ts, const float* __restrict__ obs,
    const float* __restrict__ s2g, float* __restrict__ tauS) {
  const int wid  = (blockIdx.x * 256 + threadIdx.x) >> 6;  // stream = b*4+a
  const int lane = threadIdx.x & 63;
  if (wid >= NSTREAM) return;
  const int b = wid >> 2, a = wid & 3;

  float4 ov[16];
  #pragma unroll
  for (int q = 0; q < 16; ++q) ov[q] = ((const float4*)(obs + (size_t)b * 64))[q];

  float s0 = INFINITY, s1 = INFINITY, s2v = INFINITY;   // 3 smallest
  for (int j = lane; j < NSAMP; j += 64) {
    const int c = j * 64;
    const float4* tr = (const float4*)(ts + ((size_t)a * C_ + c) * 64);
    float d0 = 0.f, d1 = 0.f, d2 = 0.f, d3 = 0.f;
    #pragma unroll
    for (int q = 0; q < 16; ++q) {
      const float4 t4 = tr[q];
      d0 = fmaf(t4.x, ov[q].x, d0); d1 = fmaf(t4.y, ov[q].y, d1);
      d2 = fmaf(t4.z, ov[q].z, d2); d3 = fmaf(t4.w, ov[q].w, d3);
    }
    const float sc = fmaf(-2.f, (d0 + d1) + (d2 + d3), s2g[a * C_ + c]);
    if (sc < s2v) {
      if (sc < s1) { s2v = s1; if (sc < s0) { s1 = s0; s0 = sc; } else s1 = sc; }
      else s2v = sc;
    }
  }
  // cross-lane merge of sorted triples -> global 3 smallest
  #pragma unroll
  for (int off = 1; off < 64; off <<= 1) {
    const float b0 = __shfl_xor(s0, off, 64);
    const float b1 = __shfl_xor(s1, off, 64);
    const float b2 = __shfl_xor(s2v, off, 64);
    const float x0 = fminf(s0, b0), y0 = fmaxf(s0, b0);
    const float x1 = fminf(s1, b1), y1 = fmaxf(s1, b1);
    const float z  = fminf(fminf(s2v, b2), y1);
    s0 = x0; s1 = fminf(y0, x1); s2v = fminf(fmaxf(y0, x1), z);
  }
  if (lane == 0) tauS[wid] = s2v;   // 3rd smallest (strict tau)
}

// ---------------- K_filter: MFMA approx scores, emit idx <= tau+margin -----
// grid 2048 = 32 Mtiles x 4 a x 16 ch; 64 thr = 1 wave; 32 rows x 16 cands/tile.
__global__ __launch_bounds__(64) void filter_kernel(
    const unsigned short* __restrict__ tsb, const unsigned short* __restrict__ obsb,
    const float* __restrict__ s2g, const float* __restrict__ tauS,
    int* __restrict__ cnt, int* __restrict__ flg, int* __restrict__ ebuf)
{
  __shared__ int qb[32][QCAP];
  __shared__ int qc[32];
  const int lane = threadIdx.x;
  const int ch = blockIdx.x & 15;
  const int a  = (blockIdx.x >> 4) & 3;
  const int mt = blockIdx.x >> 6;
  const int b0 = mt * 32;
  const int cl = lane & 15, g = lane >> 4;

  if (lane < 32) qc[lane] = 0;
  __syncthreads();

  // A-frags: obs rows b0..b0+31, symmetric k-slot layout k = s*32 + g*8 + e
  short8v oa00 = *(const short8v*)(obsb + ((size_t)(b0 +      cl)) * 64 +  0 + g * 8);
  short8v oa01 = *(const short8v*)(obsb + ((size_t)(b0 +      cl)) * 64 + 32 + g * 8);
  short8v oa10 = *(const short8v*)(obsb + ((size_t)(b0 + 16 + cl)) * 64 +  0 + g * 8);
  short8v oa11 = *(const short8v*)(obsb + ((size_t)(b0 + 16 + cl)) * 64 + 32 + g * 8);

  float tE[8];
  #pragma unroll
  for (int j = 0; j < 8; ++j) {
    const int row = g * 4 + (j & 3) + 16 * (j >> 2);
    tE[j] = tauS[(b0 + row) * 4 + a] + EMARG;
  }

  const int cb = ch * CCH;
  for (int t = 0; t < NTF; ++t) {
    const int c0 = cb + t * 16;
    const int c  = c0 + cl;
    const int cc = min(c, C_ - 1);
    const short8v tb0 = *(const short8v*)(tsb + ((size_t)a * C_ + cc) * 64 +  0 + g * 8);
    const short8v tb1 = *(const short8v*)(tsb + ((size_t)a * C_ + cc) * 64 + 32 + g * 8);
    const float s2v = s2g[a * C_ + cc];
    f32x4 ac0 = {0.f, 0.f, 0.f, 0.f}, ac1 = {0.f, 0.f, 0.f, 0.f};
    ac0 = __builtin_amdgcn_mfma_f32_16x16x32_bf16(oa00, tb0, ac0, 0, 0, 0);
    ac0 = __builtin_amdgcn_mfma_f32_16x16x32_bf16(oa01, tb1, ac0, 0, 0, 0);
    ac1 = __builtin_amdgcn_mfma_f32_16x16x32_bf16(oa10, tb0, ac1, 0, 0, 0);
    ac1 = __builtin_amdgcn_mfma_f32_16x16x32_bf16(oa11, tb1, ac1, 0, 0, 0);
    const bool valid = c < cb + CCH;
    #pragma unroll
    for (int j = 0; j < 8; ++j) {
      const float av = (j < 4) ? ac0[j] : ac1[j - 4];
      const float sc = fmaf(-2.f, av, s2v);
      const bool hit = valid && (sc <= tE[j]);
      if (__ballot(hit)) {
        if (hit) {
          const int row = g * 4 + (j & 3) + 16 * (j >> 2);
          const int p = atomicAdd(&qc[row], 1);
          if (p < QCAP) qb[row][p] = c;
        }
      }
    }
  }
  __syncthreads();

  // flush queues: one global atomic per (wave,row)
  for (int r = 0; r < 32; ++r) {
    const int n = qc[r];
    if (n == 0) continue;
    const int stream = (b0 + r) * 4 + a;
    if (n > QCAP) { if (lane == 0) flg[stream] = 1; continue; }
    int bs = 0;
    if (lane == 0) bs = atomicAdd(&cnt[stream], n);
    bs = __shfl(bs, 0, 64);
    const int wr = min(n, max(0, CAP - bs));
    for (int e = lane; e < wr; e += 64)
      ebuf[(size_t)stream * CAP + bs + e] = qb[r][e];
    if (bs + n > CAP) { if (lane == 0) flg[stream] = 1; }
  }
}

// ---------------- K_rescore: exact rescore of emitted set, verify, top-11 --
__global__ __launch_bounds__(64) void rescore_kernel(
    const float* __restrict__ ts, const float* __restrict__ obs,
    const float* __restrict__ s2g, const float* __restrict__ tauS,
    const float* __restrict__ qv, const int* __restrict__ cnt,
    int* __restrict__ flg, const int* __restrict__ ebuf, float* __restrict__ qec)
{
  __shared__ float ls[CAP];
  __shared__ int   li[CAP];
  __shared__ float pbs[16][K_NN];
  __shared__ int   pbi[16][K_NN];
  const int stream = blockIdx.x;
  const int lane = threadIdx.x;
  if (flg[stream]) return;
  const int n = cnt[stream];
  if (n < K_NN || n > CAP) { if (lane == 0) flg[stream] = 1; return; }
  const int b = stream >> 2, a = stream & 3;

  float4 ov[16];
  #pragma unroll
  for (int q = 0; q < 16; ++q) ov[q] = ((const float4*)(obs + (size_t)b * 64))[q];
  const float tv = tauS[stream];

  int cle = 0;
  for (int e = lane; e < n; e += 64) {
    const int idx = ebuf[(size_t)stream * CAP + e];
    const float4* tr = (const float4*)(ts + ((size_t)a * C_ + idx) * 64);
    float d0 = 0.f, d1 = 0.f, d2 = 0.f, d3 = 0.f;
    #pragma unroll
    for (int q = 0; q < 16; ++q) {
      const float4 t4 = tr[q];
      d0 = fmaf(t4.x, ov[q].x, d0); d1 = fmaf(t4.y, ov[q].y, d1);
      d2 = fmaf(t4.z, ov[q].z, d2); d3 = fmaf(t4.w, ov[q].w, d3);
    }
    const float sc = fmaf(-2.f, (d0 + d1) + (d2 + d3), s2g[a * C_ + idx]);
    ls[e] = sc; li[e] = idx;
    cle += (sc <= tv) ? 1 : 0;
  }
  #pragma unroll
  for (int off = 1; off < 64; off <<= 1) cle += __shfl_xor(cle, off, 64);
  __syncthreads();
  if (cle < K_NN) { if (lane == 0) flg[stream] = 1; return; }  // unsound -> fallback

  if (lane < 16) {
    float bs[K_NN]; int bi[K_NN];
    #pragma unroll
    for (int j = 0; j < K_NN; ++j) { bs[j] = INFINITY; bi[j] = 0x7fffffff; }
    for (int e = lane; e < n; e += 16) {
      const float s = ls[e]; const int i = li[e];
      INS11(bs, bi, s, i)
    }
    #pragma unroll
    for (int j = 0; j < K_NN; ++j) { pbs[lane][j] = bs[j]; pbi[lane][j] = bi[j]; }
  }
  __syncthreads();
  if (lane == 0) {
    float bs[K_NN]; int bi[K_NN];
    #pragma unroll
    for (int j = 0; j < K_NN; ++j) { bs[j] = INFINITY; bi[j] = 0x7fffffff; }
    for (int p = 0; p < 16; ++p)
      for (int j = 0; j < K_NN; ++j) {
        const float s = pbs[p][j]; const int i = pbi[p][j];
        INS11(bs, bi, s, i)
      }
    float s = 0.f;
    #pragma unroll
    for (int j = 0; j < K_NN; ++j) s += qv[(size_t)a * C_ + bi[j]];
    qec[stream] = s / (float)K_NN;
  }
}

// ---------------- K_fallback: full exact scan for flagged streams ----------
__global__ __launch_bounds__(256) void fallback_kernel(
    const float* __restrict__ ts, const float* __restrict__ obs,
    const float* __restrict__ s2g, const float* __restrict__ qv,
    const int* __restrict__ flg, float* __restrict__ qec)
{
  __shared__ float lbs[256][K_NN];
  __shared__ int   lbi[256][K_NN];
  const int stream = blockIdx.x;
  if (!flg[stream]) return;
  const int tid = threadIdx.x;
  const int b = stream >> 2, a = stream & 3;

  float4 ov[16];
  #pragma unroll
  for (int q = 0; q < 16; ++q) ov[q] = ((const float4*)(obs + (size_t)b * 64))[q];

  float bs[K_NN]; int bi[K_NN];
  #pragma unroll
  for (int j = 0; j < K_NN; ++j) { bs[j] = INFINITY; bi[j] = 0x7fffffff; }

  for (int c = tid; c < C_; c += 256) {
    const float4* tr = (const float4*)(ts + ((size_t)a * C_ + c) * 64);
    float d0 = 0.f, d1 = 0.f, d2 = 0.f, d3 = 0.f;
    #pragma unroll
    for (int q = 0; q < 16; ++q) {
      const float4 t4 = tr[q];
      d0 = fmaf(t4.x, ov[q].x, d0); d1 = fmaf(t4.y, ov[q].y, d1);
      d2 = fmaf(t4.z, ov[q].z, d2); d3 = fmaf(t4.w, ov[q].w, d3);
    }
    const float sc = fmaf(-2.f, (d0 + d1) + (d2 + d3), s2g[a * C_ + c]);
    INS11(bs, bi, sc, c)
  }
  #pragma unroll
  for (int j = 0; j < K_NN; ++j) { lbs[tid][j] = bs[j]; lbi[tid][j] = bi[j]; }
  __syncthreads();

  if (tid < 16) {
    float ms[K_NN]; int mi[K_NN];
    #pragma unroll
    for (int j = 0; j < K_NN; ++j) { ms[j] = INFINITY; mi[j] = 0x7fffffff; }
    for (int p = tid; p < 256; p += 16)
      for (int j = 0; j < K_NN; ++j) {
        const float s = lbs[p][j]; const int i = lbi[p][j];
        INS11(ms, mi, s, i)
      }
    #pragma unroll
    for (int j = 0; j < K_NN; ++j) { lbs[tid][j] = ms[j]; lbi[tid][j] = mi[j]; }
  }
  __syncthreads();
  if (tid == 0) {
    float ms[K_NN]; int mi[K_NN];
    #pragma unroll
    for (int j = 0; j < K_NN; ++j) { ms[j] = INFINITY; mi[j] = 0x7fffffff; }
    for (int p = 0; p < 16; ++p)
      for (int j = 0; j < K_NN; ++j) {
        const float s = lbs[p][j]; const int i = lbi[p][j];
        INS11(ms, mi, s, i)
      }
    float s = 0.f;
    #pragma unroll
    for (int j = 0; j < K_NN; ++j) s += qv[(size_t)a * C_ + mi[j]];
    qec[stream] = s / (float)K_NN;
  }
}

// ---------------- K_mlp: MLP + combine + argmax (unchanged, proven) --------
__global__ __launch_bounds__(256) void mlp_kernel(
    const float* __restrict__ obs, const float* __restrict__ qec,
    const float* __restrict__ W1, const float* __restrict__ b1,
    const float* __restrict__ W2, const float* __restrict__ b2,
    const float* __restrict__ W3, const float* __restrict__ b3,
    float* __restrict__ out)
{
  const int wave = threadIdx.x >> 6;
  const int lane = threadIdx.x & 63;
  const int b = blockIdx.x * 4 + wave;

  float xv = obs[(size_t)b * 64 + lane];

  float acc = b1[lane];
  #pragma unroll 8
  for (int d = 0; d < 64; ++d)
    acc = fmaf(__shfl(xv, d, 64), W1[d * 64 + lane], acc);
  float h1 = fmaxf(acc, 0.f);

  float acc2 = b2[lane];
  #pragma unroll 8
  for (int d = 0; d < 64; ++d)
    acc2 = fmaf(__shfl(h1, d, 64), W2[d * 64 + lane], acc2);
  float h2 = fmaxf(acc2, 0.f);

  float p0 = h2 * W3[lane * 4 + 0];
  float p1 = h2 * W3[lane * 4 + 1];
  float p2 = h2 * W3[lane * 4 + 2];
  float p3 = h2 * W3[lane * 4 + 3];
  #pragma unroll
  for (int off = 32; off > 0; off >>= 1) {
    p0 += __shfl_xor(p0, off, 64);
    p1 += __shfl_xor(p1, off, 64);
    p2 += __shfl_xor(p2, off, 64);
    p3 += __shfl_xor(p3, off, 64);
  }

  if (lane == 0) {
    float q0 = 0.5f * (qec[b * 4 + 0] + (p0 + b3[0]));
    float q1 = 0.5f * (qec[b * 4 + 1] + (p1 + b3[1]));
    float q2 = 0.5f * (qec[b * 4 + 2] + (p2 + b3[2]));
    float q3 = 0.5f * (qec[b * 4 + 3] + (p3 + b3[3]));
    int am = 0; float m = q0;
    if (q1 > m) { m = q1; am = 1; }
    if (q2 > m) { m = q2; am = 2; }
    if (q3 > m) { m = q3; am = 3; }
    out[b] = (float)am;
    float* qrow = out + B_ + (size_t)b * 4;
    qrow[0] = q0; qrow[1] = q1; qrow[2] = q2; qrow[3] = q3;
  }
}

extern "C" void kernel_launch(void* const* d_in, const int* in_sizes, int n_in,
                              void* d_out, int out_size, void* d_ws, size_t ws_size,
                              hipStream_t stream) {
  const float* obs = (const float*)d_in[0];
  const float* ts  = (const float*)d_in[1];
  const float* qv  = (const float*)d_in[2];
  const float* W1  = (const float*)d_in[3];
  const float* b1  = (const float*)d_in[4];
  const float* W2  = (const float*)d_in[5];
  const float* b2  = (const float*)d_in[6];
  const float* W3  = (const float*)d_in[7];
  const float* b3  = (const float*)d_in[8];
  float* out = (float*)d_out;

  // ws layout (all 16B-aligned): ~39.2 MB total
  unsigned short* tsb  = (unsigned short*)d_ws;                 // A*C*64 bf16
  unsigned short* obsb = tsb + (size_t)A_ * C_ * 64;            // B*64 bf16
  float* s2g  = (float*)(obsb + (size_t)B_ * 64);               // A*C
  float* tauS = s2g + (size_t)A_ * C_;                          // 4096
  int*   cnt  = (int*)(tauS + NSTREAM);                         // 4096
  int*   flg  = cnt + NSTREAM;                                  // 4096
  int*   ebuf = flg + NSTREAM;                                  // 4096*CAP
  float* qec  = (float*)(ebuf + (size_t)NSTREAM * CAP);         // 4096

  hipMemsetAsync(cnt, 0, NSTREAM * 2 * sizeof(int), stream);    // cnt + flg

  s2_kernel<<<dim3((A_ * C_ / 16 + 3) / 4), dim3(256), 0, stream>>>(ts, s2g);
  prep_kernel<<<dim3(2048), dim3(256), 0, stream>>>(ts, obs, tsb, obsb);
  sample_kernel<<<dim3(NSTREAM / 4), dim3(256), 0, stream>>>(ts, obs, s2g, tauS);
  filter_kernel<<<dim3(32 * 4 * NCH), dim3(64), 0, stream>>>(tsb, obsb, s2g, tauS,
                                                             cnt, flg, ebuf);
  rescore_kernel<<<dim3(NSTREAM), dim3(64), 0, stream>>>(ts, obs, s2g, tauS, qv,
                                                         cnt, flg, ebuf, qec);
  fallback_kernel<<<dim3(NSTREAM), dim3(256), 0, stream>>>(ts, obs, s2g, qv, flg, qec);
  mlp_kernel<<<dim3(B_ / 4), dim3(256), 0, stream>>>(obs, qec, W1, b1, W2, b2, W3, b3, out);
}